// Round 2
// baseline (3296.914 us; speedup 1.0000x reference)
//
#include <hip/hip_runtime.h>
#include <cfloat>
#include <cstdint>
#include <cstddef>

#define N_ROWS 32768
#define K_CODES 8192
#define DIM 512
#define BETA 0.25

// main GEMM tile params
#define BM 128
#define BN 128
#define BKD 32
#define CSPLIT 8
#define CODES_PER_CHUNK (K_CODES / CSPLIT)  // 1024
#define LSTRIDE 132                          // padded k-major LDS stride

// ---------------- K0: numpy-exact fp32 pairwise sum of z*z per row ----------------
// Replicates numpy pairwise_sum scalar model for n=512 contiguous f32:
//   s = ((leaf(0)+leaf(128)) + (leaf(256)+leaf(384)))
//   leaf(b): r[j]=x[b+j]; for i=8..120 step 8: r[j]+=x[b+i+j];
//            ((r0+r1)+(r2+r3))+((r4+r5)+(r6+r7)),  x[d]=fl(z_d*z_d)
// __fmul_rn/__fadd_rn prevent FMA contraction (numpy rounds z*z to f32 first).
__global__ __launch_bounds__(256)
void vq_s1(const float* __restrict__ z, float* __restrict__ s1out) {
  int row = blockIdx.x * 256 + threadIdx.x;
  const float* p = z + (size_t)row * DIM;
  float lf[4];
#pragma unroll
  for (int L = 0; L < 4; ++L) {
    const float* q = p + L * 128;
    float r[8];
#pragma unroll
    for (int j = 0; j < 8; ++j) r[j] = __fmul_rn(q[j], q[j]);
    for (int i = 8; i < 128; i += 8) {
#pragma unroll
      for (int j = 0; j < 8; ++j)
        r[j] = __fadd_rn(r[j], __fmul_rn(q[i + j], q[i + j]));
    }
    float s01 = __fadd_rn(r[0], r[1]);
    float s23 = __fadd_rn(r[2], r[3]);
    float s45 = __fadd_rn(r[4], r[5]);
    float s67 = __fadd_rn(r[6], r[7]);
    lf[L] = __fadd_rn(__fadd_rn(s01, s23), __fadd_rn(s45, s67));
  }
  s1out[row] = __fadd_rn(__fadd_rn(lf[0], lf[1]), __fadd_rn(lf[2], lf[3]));
}

// ---------------- K1: fp32 chained-FMA GEMM (sgemm-bitwise model) + quantized argmin --
// M_rc = chained fmaf over k=0..511 ascending, one accumulator per element
// d_rc = fl32(s1_r - 2*M_rc)   (== numpy's (s1+s2)-2M since s2 < 1/2 ulp(s1))
// argmin with first-index tie-break over the fp32-quantized d.
__global__ __launch_bounds__(256)
void vq_main(const float* __restrict__ z, const float* __restrict__ cb,
             const float* __restrict__ s1, float* __restrict__ b1s,
             int* __restrict__ i1s) {
  __shared__ float As[BKD * LSTRIDE];
  __shared__ float Bs[BKD * LSTRIDE];
  const int tid = threadIdx.x;
  const int tx = tid & 15;
  const int ty = tid >> 4;
  const int row0 = blockIdx.x * BM;
  const int chunk = blockIdx.y;
  const int code0 = chunk * CODES_PER_CHUNK;

  float s1v[8];
#pragma unroll
  for (int i = 0; i < 8; ++i) s1v[i] = s1[row0 + ty * 8 + i];

  float rb1[8];
  int ri1[8];
#pragma unroll
  for (int i = 0; i < 8; ++i) { rb1[i] = FLT_MAX; ri1[i] = 0x7fffffff; }

  for (int ct = 0; ct < CODES_PER_CHUNK / BN; ++ct) {
    const int col0 = code0 + ct * BN;
    float acc[8][8];
#pragma unroll
    for (int i = 0; i < 8; ++i)
#pragma unroll
      for (int j = 0; j < 8; ++j) acc[i][j] = 0.f;

    for (int dk = 0; dk < DIM; dk += BKD) {
      __syncthreads();  // protect previous iteration's LDS reads
#pragma unroll
      for (int i = 0; i < 4; ++i) {
        int lin = tid + i * 256;  // 0..1023
        int r = lin >> 3;         // 0..127
        int kq = lin & 7;         // 0..7
        float4 va = *(const float4*)&z[(size_t)(row0 + r) * DIM + dk + kq * 4];
        As[(kq * 4 + 0) * LSTRIDE + r] = va.x;
        As[(kq * 4 + 1) * LSTRIDE + r] = va.y;
        As[(kq * 4 + 2) * LSTRIDE + r] = va.z;
        As[(kq * 4 + 3) * LSTRIDE + r] = va.w;
        float4 vb = *(const float4*)&cb[(size_t)(col0 + r) * DIM + dk + kq * 4];
        Bs[(kq * 4 + 0) * LSTRIDE + r] = vb.x;
        Bs[(kq * 4 + 1) * LSTRIDE + r] = vb.y;
        Bs[(kq * 4 + 2) * LSTRIDE + r] = vb.z;
        Bs[(kq * 4 + 3) * LSTRIDE + r] = vb.w;
      }
      __syncthreads();
#pragma unroll
      for (int k = 0; k < BKD; ++k) {
        float a[8], b[8];
        *(float4*)&a[0] = *(const float4*)&As[k * LSTRIDE + ty * 8];
        *(float4*)&a[4] = *(const float4*)&As[k * LSTRIDE + ty * 8 + 4];
        *(float4*)&b[0] = *(const float4*)&Bs[k * LSTRIDE + tx * 8];
        *(float4*)&b[4] = *(const float4*)&Bs[k * LSTRIDE + tx * 8 + 4];
#pragma unroll
        for (int i = 0; i < 8; ++i)
#pragma unroll
          for (int j = 0; j < 8; ++j) acc[i][j] = fmaf(a[i], b[j], acc[i][j]);
      }
    }
    // fold quantized distances; ascending idx per thread + strict < keeps first index
#pragma unroll
    for (int j = 0; j < 8; ++j) {
      int idx = col0 + tx * 8 + j;
#pragma unroll
      for (int i = 0; i < 8; ++i) {
        float dq = __fsub_rn(s1v[i], __fmul_rn(2.0f, acc[i][j]));
        if (dq < rb1[i]) { rb1[i] = dq; ri1[i] = idx; }
      }
    }
  }

  // cross-tx merge (16 threads/row), lexicographic (score, idx) min
#pragma unroll
  for (int i = 0; i < 8; ++i) {
    float v1 = rb1[i];
    int ix = ri1[i];
#pragma unroll
    for (int m = 8; m >= 1; m >>= 1) {
      float o1 = __shfl_xor(v1, m, 64);
      int oi = __shfl_xor(ix, m, 64);
      bool oless = (o1 < v1) || (o1 == v1 && oi < ix);
      v1 = oless ? o1 : v1;
      ix = oless ? oi : ix;
    }
    if (tx == 0) {
      int row = row0 + ty * 8 + i;
      b1s[row * CSPLIT + chunk] = v1;
      i1s[row * CSPLIT + chunk] = ix;
    }
  }
}

// ---------------- K2: merge chunks; gather z_q; per-row loss (f64) ----------------
__global__ __launch_bounds__(256)
void vq_finalize(const float* __restrict__ z, const float* __restrict__ cb,
                 const float* __restrict__ b1s, const int* __restrict__ i1s,
                 float* __restrict__ out, double* __restrict__ loss64) {
  int wid = threadIdx.x >> 6, lane = threadIdx.x & 63;
  int row = blockIdx.x * 4 + wid;
  float B1 = FLT_MAX;
  int I1 = 0x7fffffff;
#pragma unroll
  for (int c = 0; c < CSPLIT; ++c) {
    float cb1 = b1s[row * CSPLIT + c];
    int ci1 = i1s[row * CSPLIT + c];
    if (cb1 < B1 || (cb1 == B1 && ci1 < I1)) { B1 = cb1; I1 = ci1; }
  }
  const float* zp = z + (size_t)row * DIM + lane * 8;
  const float* cp = cb + (size_t)I1 * DIM + lane * 8;
  float4 z0 = *(const float4*)zp, z1 = *(const float4*)(zp + 4);
  float4 c0 = *(const float4*)cp, c1 = *(const float4*)(cp + 4);
  *(float4*)&out[(size_t)row * DIM + lane * 8] = c0;
  *(float4*)&out[(size_t)row * DIM + lane * 8 + 4] = c1;
  double s = 0.0, d;
  d = (double)z0.x - c0.x; s += d * d;
  d = (double)z0.y - c0.y; s += d * d;
  d = (double)z0.z - c0.z; s += d * d;
  d = (double)z0.w - c0.w; s += d * d;
  d = (double)z1.x - c1.x; s += d * d;
  d = (double)z1.y - c1.y; s += d * d;
  d = (double)z1.z - c1.z; s += d * d;
  d = (double)z1.w - c1.w; s += d * d;
#pragma unroll
  for (int m = 32; m >= 1; m >>= 1) s += __shfl_down(s, m, 64);
  if (lane == 0) {
    loss64[row] = s;
    out[(size_t)N_ROWS * DIM + row] = (float)I1;
  }
}

// ---------------- K3: deterministic loss reduction ----------------
__global__ __launch_bounds__(256)
void vq_loss(const double* __restrict__ loss64, float* __restrict__ out) {
  __shared__ double sd[256];
  double s = 0.0;
  for (int i = threadIdx.x; i < N_ROWS; i += 256) s += loss64[i];
  sd[threadIdx.x] = s;
  __syncthreads();
  for (int k = 128; k > 0; k >>= 1) {
    if (threadIdx.x < k) sd[threadIdx.x] += sd[threadIdx.x + k];
    __syncthreads();
  }
  if (threadIdx.x == 0)
    out[(size_t)N_ROWS * DIM + N_ROWS] =
        (float)(BETA * sd[0] / ((double)N_ROWS * (double)DIM));
}

extern "C" void kernel_launch(void* const* d_in, const int* in_sizes, int n_in,
                              void* d_out, int out_size, void* d_ws, size_t ws_size,
                              hipStream_t stream) {
  const float* z = (const float*)d_in[0];
  const float* cb = (const float*)d_in[1];
  float* out = (float*)d_out;
  char* ws = (char*)d_ws;

  // ws layout (bytes): total ~2.4 MB
  float* s1f = (float*)(ws + 0);                  // 32768*4   = 131072
  double* loss64 = (double*)(ws + 131072);        // 32768*8   = 262144
  float* b1s = (float*)(ws + 393216);             // 32768*8*4 = 1048576
  int* i1s = (int*)(ws + 393216 + 1048576);       // 1048576

  vq_s1<<<N_ROWS / 256, 256, 0, stream>>>(z, s1f);
  vq_main<<<dim3(N_ROWS / BM, CSPLIT), 256, 0, stream>>>(z, cb, s1f, b1s, i1s);
  vq_finalize<<<N_ROWS / 4, 256, 0, stream>>>(z, cb, b1s, i1s, out, loss64);
  vq_loss<<<1, 256, 0, stream>>>(loss64, out);
}

// Round 3
// 934.292 us; speedup vs baseline: 3.5288x; 3.5288x over previous
//
#include <hip/hip_runtime.h>
#include <cfloat>
#include <cstdint>
#include <cstddef>

#define N_ROWS 32768
#define K_CODES 8192
#define DIM 512
#define BETA 0.25

typedef unsigned short u16;
typedef _Float16 half8 __attribute__((ext_vector_type(8)));
typedef float f32x4 __attribute__((ext_vector_type(4)));

#define LDAP 40       // padded halves per LDS row (80 B, 16B-aligned)
#define OVCAP 2048    // per-block LDS overflow buffer entries
#define DELTA_A 0.4f  // append window on scaled dot (bound needs 0.213)

__device__ inline u16 f2h(float x) {
  union { _Float16 h; u16 u; } c;
  c.h = (_Float16)x;
  return c.u;
}

// ---------------- cvt: f32 -> f16 (optionally scaled), 8 elems/thread ----------------
__global__ __launch_bounds__(256)
void vq_cvt(const float* __restrict__ src, u16* __restrict__ dst, float scale,
            int n8, int* ovcnt_reset) {
  if (ovcnt_reset != nullptr && blockIdx.x == 0 && threadIdx.x == 0) *ovcnt_reset = 0;
  int i = blockIdx.x * 256 + threadIdx.x;
  if (i >= n8) return;
  float4 a = ((const float4*)src)[(size_t)i * 2];
  float4 b = ((const float4*)src)[(size_t)i * 2 + 1];
  uint4 o;
  o.x = (unsigned)f2h(a.x * scale) | ((unsigned)f2h(a.y * scale) << 16);
  o.y = (unsigned)f2h(a.z * scale) | ((unsigned)f2h(a.w * scale) << 16);
  o.z = (unsigned)f2h(b.x * scale) | ((unsigned)f2h(b.y * scale) << 16);
  o.w = (unsigned)f2h(b.z * scale) | ((unsigned)f2h(b.w * scale) << 16);
  ((uint4*)dst)[i] = o;
}

// ---------------- s1: numpy-exact fp32 pairwise sum of z*z per row (validated) -------
__global__ __launch_bounds__(256)
void vq_s1(const float* __restrict__ z, float* __restrict__ s1out) {
  int row = blockIdx.x * 256 + threadIdx.x;
  const float* p = z + (size_t)row * DIM;
  float lf[4];
#pragma unroll
  for (int L = 0; L < 4; ++L) {
    const float* q = p + L * 128;
    float r[8];
#pragma unroll
    for (int j = 0; j < 8; ++j) r[j] = __fmul_rn(q[j], q[j]);
    for (int i = 8; i < 128; i += 8) {
#pragma unroll
      for (int j = 0; j < 8; ++j)
        r[j] = __fadd_rn(r[j], __fmul_rn(q[i + j], q[i + j]));
    }
    float s01 = __fadd_rn(r[0], r[1]);
    float s23 = __fadd_rn(r[2], r[3]);
    float s45 = __fadd_rn(r[4], r[5]);
    float s67 = __fadd_rn(r[6], r[7]);
    lf[L] = __fadd_rn(__fadd_rn(s01, s23), __fadd_rn(s45, s67));
  }
  s1out[row] = __fadd_rn(__fadd_rn(lf[0], lf[1]), __fadd_rn(lf[2], lf[3]));
}

// ---------------- gemm: f16 MFMA, per-row tile-max + near-max append ----------------
// grid (64 coltiles, 256 rowtiles), 256 threads = 4 waves, each wave 32 rows x 128 cols
__global__ __launch_bounds__(256)
void vq_gemm(const u16* __restrict__ zh, const u16* __restrict__ ch,
             float* __restrict__ tilemax, uint2* __restrict__ ovlist,
             int* __restrict__ ovcnt, int gcap) {
  __shared__ u16 Ah[128 * LDAP];
  __shared__ u16 Bh[128 * LDAP];
  __shared__ uint2 obuf[OVCAP];
  __shared__ int ocnt, gbase;
  const int tid = threadIdx.x;
  const int lane = tid & 63;
  const int wid = tid >> 6;
  const int col0 = blockIdx.x * 128;
  const int row0 = blockIdx.y * 128;
  if (tid == 0) ocnt = 0;

  f32x4 acc[2][8];
#pragma unroll
  for (int a = 0; a < 2; ++a)
#pragma unroll
    for (int b = 0; b < 8; ++b) acc[a][b] = (f32x4){0.f, 0.f, 0.f, 0.f};

  const int sr = tid >> 2;         // staging row 0..63 (also +64)
  const int sk = (tid & 3) * 8;    // halves offset within 32-k step

  for (int dk = 0; dk < DIM; dk += 32) {
    __syncthreads();
    *(uint4*)&Ah[sr * LDAP + sk] =
        *(const uint4*)&zh[(size_t)(row0 + sr) * DIM + dk + sk];
    *(uint4*)&Ah[(sr + 64) * LDAP + sk] =
        *(const uint4*)&zh[(size_t)(row0 + sr + 64) * DIM + dk + sk];
    *(uint4*)&Bh[sr * LDAP + sk] =
        *(const uint4*)&ch[(size_t)(col0 + sr) * DIM + dk + sk];
    *(uint4*)&Bh[(sr + 64) * LDAP + sk] =
        *(const uint4*)&ch[(size_t)(col0 + sr + 64) * DIM + dk + sk];
    __syncthreads();
    half8 af[2], bf[8];
    const int koff = (lane >> 4) * 8;
    const int rsub = lane & 15;
#pragma unroll
    for (int mi = 0; mi < 2; ++mi)
      af[mi] = *(const half8*)&Ah[(wid * 32 + mi * 16 + rsub) * LDAP + koff];
#pragma unroll
    for (int nj = 0; nj < 8; ++nj)
      bf[nj] = *(const half8*)&Bh[(nj * 16 + rsub) * LDAP + koff];
#pragma unroll
    for (int mi = 0; mi < 2; ++mi)
#pragma unroll
      for (int nj = 0; nj < 8; ++nj)
        acc[mi][nj] =
            __builtin_amdgcn_mfma_f32_16x16x32_f16(af[mi], bf[nj], acc[mi][nj], 0, 0, 0);
  }

  // epilogue: per-row max over the 128-col tile, then threshold-append
#pragma unroll
  for (int mi = 0; mi < 2; ++mi) {
#pragma unroll
    for (int rg = 0; rg < 4; ++rg) {
      float m = acc[mi][0][rg];
#pragma unroll
      for (int nj = 1; nj < 8; ++nj) m = fmaxf(m, acc[mi][nj][rg]);
#pragma unroll
      for (int s = 1; s <= 8; s <<= 1) m = fmaxf(m, __shfl_xor(m, s, 64));
      const int grow = row0 + wid * 32 + mi * 16 + (lane >> 4) * 4 + rg;
      if ((lane & 15) == 0) tilemax[(size_t)blockIdx.x * N_ROWS + grow] = m;
      const float thr = m - DELTA_A;
#pragma unroll
      for (int nj = 0; nj < 8; ++nj) {
        float v = acc[mi][nj][rg];
        if (v >= thr) {
          const int code = col0 + nj * 16 + (lane & 15);
          uint2 e = make_uint2(((unsigned)grow << 13) | (unsigned)code,
                               __float_as_uint(v));
          int p = atomicAdd(&ocnt, 1);
          if (p < OVCAP) obuf[p] = e;
          else {
            int g = atomicAdd(ovcnt, 1);
            if (g < gcap) ovlist[g] = e;
          }
        }
      }
    }
  }
  __syncthreads();
  int n = ocnt < OVCAP ? ocnt : OVCAP;
  if (tid == 0) gbase = atomicAdd(ovcnt, n);
  __syncthreads();
  for (int i = tid; i < n; i += 256) {
    int g = gbase + i;
    if (g < gcap) ovlist[g] = obuf[i];
  }
}

// ---------------- merge: per-row global max -> filter threshold; init win -----------
__global__ __launch_bounds__(256)
void vq_merge(const float* __restrict__ tilemax, float* __restrict__ mthr,
              unsigned long long* __restrict__ win) {
  int row = blockIdx.x * 256 + threadIdx.x;
  float g = -1e30f;
  for (int t = 0; t < 64; ++t) g = fmaxf(g, tilemax[(size_t)t * N_ROWS + row]);
  mthr[row] = g - DELTA_A;
  win[row] = ~0ULL;
}

__global__ __launch_bounds__(256)
void vq_init(unsigned long long* __restrict__ win) {
  int row = blockIdx.x * 256 + threadIdx.x;
  win[row] = ~0ULL;
}

// ---------------- overflow: filter + exact fp32 chain re-rank ----------------
__global__ __launch_bounds__(256)
void vq_overflow(const float* __restrict__ z, const float* __restrict__ cb,
                 const float* __restrict__ s1, const float* __restrict__ mthr,
                 const uint2* __restrict__ ovlist, const int* __restrict__ ovcnt,
                 int gcap, unsigned long long* __restrict__ win) {
  int n = *ovcnt;
  if (n > gcap) n = gcap;
  for (int i = blockIdx.x * 256 + threadIdx.x; i < n; i += gridDim.x * 256) {
    uint2 e = ovlist[i];
    int row = e.x >> 13;
    int code = e.x & 8191;
    if (__uint_as_float(e.y) < mthr[row]) continue;
    const float* zp = z + (size_t)row * DIM;
    const float* cp = cb + (size_t)code * DIM;
    float acc = 0.f;
    for (int k = 0; k < DIM; k += 4) {
      float4 zv = *(const float4*)(zp + k);
      float4 cv = *(const float4*)(cp + k);
      acc = fmaf(zv.x, cv.x, acc);
      acc = fmaf(zv.y, cv.y, acc);
      acc = fmaf(zv.z, cv.z, acc);
      acc = fmaf(zv.w, cv.w, acc);
    }
    float dq = __fsub_rn(s1[row], __fmul_rn(2.0f, acc));
    unsigned long long key =
        ((unsigned long long)__float_as_uint(dq) << 32) | (unsigned)code;
    atomicMin(&win[row], key);
  }
}

// ---------------- fallback: gated full exact scan (overflow safety) ----------------
__global__ __launch_bounds__(256)
void vq_fallback(const float* __restrict__ z, const float* __restrict__ cb,
                 const float* __restrict__ s1, const int* __restrict__ ovcnt,
                 int gcap, int force, unsigned long long* __restrict__ win) {
  if (!force && *ovcnt <= gcap) return;
  __shared__ float zrow[DIM];
  __shared__ unsigned long long red[256];
  for (int row = blockIdx.x; row < N_ROWS; row += gridDim.x) {
    __syncthreads();
    for (int t = threadIdx.x; t < DIM; t += 256) zrow[t] = z[(size_t)row * DIM + t];
    __syncthreads();
    float s1v = s1[row];
    unsigned long long best = ~0ULL;
    for (int j = threadIdx.x; j < K_CODES; j += 256) {
      const float* cp = cb + (size_t)j * DIM;
      float acc = 0.f;
      for (int k = 0; k < DIM; ++k) acc = fmaf(zrow[k], cp[k], acc);
      float dq = __fsub_rn(s1v, __fmul_rn(2.0f, acc));
      unsigned long long key =
          ((unsigned long long)__float_as_uint(dq) << 32) | (unsigned)j;
      if (key < best) best = key;
    }
    red[threadIdx.x] = best;
    __syncthreads();
    for (int s = 128; s > 0; s >>= 1) {
      if (threadIdx.x < s && red[threadIdx.x + s] < red[threadIdx.x])
        red[threadIdx.x] = red[threadIdx.x + s];
      __syncthreads();
    }
    if (threadIdx.x == 0) atomicMin(&win[row], red[0]);
    __syncthreads();
  }
}

// ---------------- out: gather z_q, write indices, per-row loss (f64) ----------------
__global__ __launch_bounds__(256)
void vq_out(const float* __restrict__ z, const float* __restrict__ cb,
            const unsigned long long* __restrict__ win, float* __restrict__ out,
            double* __restrict__ loss64) {
  int wid = threadIdx.x >> 6, lane = threadIdx.x & 63;
  int row = blockIdx.x * 4 + wid;
  int I1 = (int)(win[row] & 8191ULL);
  const float* zp = z + (size_t)row * DIM + lane * 8;
  const float* cp = cb + (size_t)I1 * DIM + lane * 8;
  float4 z0 = *(const float4*)zp, z1 = *(const float4*)(zp + 4);
  float4 c0 = *(const float4*)cp, c1 = *(const float4*)(cp + 4);
  *(float4*)&out[(size_t)row * DIM + lane * 8] = c0;
  *(float4*)&out[(size_t)row * DIM + lane * 8 + 4] = c1;
  double s = 0.0, d;
  d = (double)z0.x - c0.x; s += d * d;
  d = (double)z0.y - c0.y; s += d * d;
  d = (double)z0.z - c0.z; s += d * d;
  d = (double)z0.w - c0.w; s += d * d;
  d = (double)z1.x - c1.x; s += d * d;
  d = (double)z1.y - c1.y; s += d * d;
  d = (double)z1.z - c1.z; s += d * d;
  d = (double)z1.w - c1.w; s += d * d;
#pragma unroll
  for (int m = 32; m >= 1; m >>= 1) s += __shfl_down(s, m, 64);
  if (lane == 0) {
    loss64[row] = s;
    out[(size_t)N_ROWS * DIM + row] = (float)I1;
  }
}

// ---------------- loss: deterministic reduction ----------------
__global__ __launch_bounds__(256)
void vq_loss(const double* __restrict__ loss64, float* __restrict__ out) {
  __shared__ double sd[256];
  double s = 0.0;
  for (int i = threadIdx.x; i < N_ROWS; i += 256) s += loss64[i];
  sd[threadIdx.x] = s;
  __syncthreads();
  for (int k = 128; k > 0; k >>= 1) {
    if (threadIdx.x < k) sd[threadIdx.x] += sd[threadIdx.x + k];
    __syncthreads();
  }
  if (threadIdx.x == 0)
    out[(size_t)N_ROWS * DIM + N_ROWS] =
        (float)(BETA * sd[0] / ((double)N_ROWS * (double)DIM));
}

extern "C" void kernel_launch(void* const* d_in, const int* in_sizes, int n_in,
                              void* d_out, int out_size, void* d_ws, size_t ws_size,
                              hipStream_t stream) {
  const float* z = (const float*)d_in[0];
  const float* cb = (const float*)d_in[1];
  float* out = (float*)d_out;
  char* ws = (char*)d_ws;

  // fast-path ws layout
  const size_t OFF_ZH = 0;                         // 33,554,432
  const size_t OFF_CH = 33554432;                  //  8,388,608
  const size_t OFF_S1 = 41943040;                  //    131,072
  const size_t OFF_MT = 42074112;                  //    131,072
  const size_t OFF_WIN = 42205184;                 //    262,144
  const size_t OFF_L64 = 42467328;                 //    262,144
  const size_t OFF_TM = 42729472;                  //  8,388,608
  const size_t OFF_OC = 51118080;                  //         16
  const size_t OFF_OV = 51118096;                  // list...
  const size_t MIN_FAST = OFF_OV + (size_t)8 * 1024 * 1024;  // need some list room

  if (ws_size >= MIN_FAST) {
    u16* zh = (u16*)(ws + OFF_ZH);
    u16* ch = (u16*)(ws + OFF_CH);
    float* s1f = (float*)(ws + OFF_S1);
    float* mthr = (float*)(ws + OFF_MT);
    unsigned long long* win = (unsigned long long*)(ws + OFF_WIN);
    double* loss64 = (double*)(ws + OFF_L64);
    float* tilemax = (float*)(ws + OFF_TM);
    int* ovcnt = (int*)(ws + OFF_OC);
    uint2* ovlist = (uint2*)(ws + OFF_OV);
    long long gc = (long long)(ws_size - OFF_OV) / 8;
    if (gc > 6 * 1024 * 1024) gc = 6 * 1024 * 1024;
    int gcap = (int)gc;

    vq_cvt<<<N_ROWS * DIM / 8 / 256, 256, 0, stream>>>(z, zh, 1.0f,
                                                       N_ROWS * DIM / 8, ovcnt);
    vq_cvt<<<K_CODES * DIM / 8 / 256, 256, 0, stream>>>(cb, ch, 4096.0f,
                                                        K_CODES * DIM / 8, nullptr);
    vq_s1<<<N_ROWS / 256, 256, 0, stream>>>(z, s1f);
    vq_gemm<<<dim3(K_CODES / 128, N_ROWS / 128), 256, 0, stream>>>(
        zh, ch, tilemax, ovlist, ovcnt, gcap);
    vq_merge<<<N_ROWS / 256, 256, 0, stream>>>(tilemax, mthr, win);
    vq_overflow<<<2048, 256, 0, stream>>>(z, cb, s1f, mthr, ovlist, ovcnt, gcap, win);
    vq_fallback<<<2048, 256, 0, stream>>>(z, cb, s1f, ovcnt, gcap, 0, win);
    vq_out<<<N_ROWS / 4, 256, 0, stream>>>(z, cb, win, out, loss64);
    vq_loss<<<1, 256, 0, stream>>>(loss64, out);
  } else {
    // tiny-ws safe path: exact full scan
    float* s1f = (float*)(ws + 0);                        // 131,072
    unsigned long long* win = (unsigned long long*)(ws + 131072);  // 262,144
    double* loss64 = (double*)(ws + 393216);              // 262,144
    vq_s1<<<N_ROWS / 256, 256, 0, stream>>>(z, s1f);
    vq_init<<<N_ROWS / 256, 256, 0, stream>>>(win);
    vq_fallback<<<2048, 256, 0, stream>>>(z, cb, s1f, nullptr, 0, 1, win);
    vq_out<<<N_ROWS / 4, 256, 0, stream>>>(z, cb, win, out, loss64);
    vq_loss<<<1, 256, 0, stream>>>(loss64, out);
  }
}

// Round 4
// 899.547 us; speedup vs baseline: 3.6651x; 1.0386x over previous
//
#include <hip/hip_runtime.h>
#include <cfloat>
#include <cstdint>
#include <cstddef>

#define N_ROWS 32768
#define K_CODES 8192
#define DIM 512
#define BETA 0.25

typedef unsigned short u16;
typedef _Float16 half8 __attribute__((ext_vector_type(8)));
typedef float f32x4 __attribute__((ext_vector_type(4)));

#define BKH 64        // k-halves per LDS tile
#define OVCAP 1024    // per-block LDS overflow buffer entries
#define DELTA_A 0.4f  // append window on scaled dot (bound needs 0.213)

#define GLOAD_LDS16(g, l)                                          \
  __builtin_amdgcn_global_load_lds(                                \
      (const __attribute__((address_space(1))) void*)(g),          \
      (__attribute__((address_space(3))) void*)(l), 16, 0, 0)

__device__ inline u16 f2h(float x) {
  union { _Float16 h; u16 u; } c;
  c.h = (_Float16)x;
  return c.u;
}

// ---------------- cvt: f32 -> f16 (optionally scaled), 8 elems/thread ----------------
__global__ __launch_bounds__(256)
void vq_cvt(const float* __restrict__ src, u16* __restrict__ dst, float scale,
            int n8, int* ovcnt_reset) {
  if (ovcnt_reset != nullptr && blockIdx.x == 0 && threadIdx.x == 0) *ovcnt_reset = 0;
  int i = blockIdx.x * 256 + threadIdx.x;
  if (i >= n8) return;
  float4 a = ((const float4*)src)[(size_t)i * 2];
  float4 b = ((const float4*)src)[(size_t)i * 2 + 1];
  uint4 o;
  o.x = (unsigned)f2h(a.x * scale) | ((unsigned)f2h(a.y * scale) << 16);
  o.y = (unsigned)f2h(a.z * scale) | ((unsigned)f2h(a.w * scale) << 16);
  o.z = (unsigned)f2h(b.x * scale) | ((unsigned)f2h(b.y * scale) << 16);
  o.w = (unsigned)f2h(b.z * scale) | ((unsigned)f2h(b.w * scale) << 16);
  ((uint4*)dst)[i] = o;
}

// ---------------- s1: numpy-exact fp32 pairwise sum of z*z per row (validated) -------
__global__ __launch_bounds__(256)
void vq_s1(const float* __restrict__ z, float* __restrict__ s1out) {
  int row = blockIdx.x * 256 + threadIdx.x;
  const float* p = z + (size_t)row * DIM;
  float lf[4];
#pragma unroll
  for (int L = 0; L < 4; ++L) {
    const float* q = p + L * 128;
    float r[8];
#pragma unroll
    for (int j = 0; j < 8; ++j) r[j] = __fmul_rn(q[j], q[j]);
    for (int i = 8; i < 128; i += 8) {
#pragma unroll
      for (int j = 0; j < 8; ++j)
        r[j] = __fadd_rn(r[j], __fmul_rn(q[i + j], q[i + j]));
    }
    float s01 = __fadd_rn(r[0], r[1]);
    float s23 = __fadd_rn(r[2], r[3]);
    float s45 = __fadd_rn(r[4], r[5]);
    float s67 = __fadd_rn(r[6], r[7]);
    lf[L] = __fadd_rn(__fadd_rn(s01, s23), __fadd_rn(s45, s67));
  }
  s1out[row] = __fadd_rn(__fadd_rn(lf[0], lf[1]), __fadd_rn(lf[2], lf[3]));
}

// ---------------- gemm: m97-structure f16 MFMA + tile-max + near-max append ----------
// 128x128 tile, BK=64, 4 waves (2x2), each wave 64x64 out via 4x4 16x16x32 frags.
// LDS layout: [128 rows][64 halves] = 128B/row, XOR-swizzled: phys = nom ^ ((row&7)<<4).
// global_load_lds writes linearly -> global SOURCE is pre-swizzled (rule #21).
__global__ __launch_bounds__(256)
void vq_gemm(const u16* __restrict__ zh, const u16* __restrict__ ch,
             float* __restrict__ tilemax, uint2* __restrict__ ovlist,
             int* __restrict__ ovcnt, int gcap) {
  __shared__ u16 Ah[128 * BKH];
  __shared__ u16 Bh[128 * BKH];
  __shared__ float rmaxw[2][128];
  __shared__ uint2 obuf[OVCAP];
  __shared__ int ocnt, gbase;
  const int tid = threadIdx.x;
  const int lane = tid & 63;
  const int wid = tid >> 6;
  const int col0 = blockIdx.x * 128;
  const int row0 = blockIdx.y * 128;
  const int wr = (wid >> 1) * 64;  // wave row offset in tile
  const int wc = (wid & 1) * 64;   // wave col offset in tile
  if (tid == 0) ocnt = 0;

  f32x4 acc[4][4];
#pragma unroll
  for (int m = 0; m < 4; ++m)
#pragma unroll
    for (int n = 0; n < 4; ++n) acc[m][n] = (f32x4){0.f, 0.f, 0.f, 0.f};

  // staging: 16 gload_lds instrs per matrix (1KB each), 4 per wave.
  // physical LDS byte p = (wid*4+j)*1024 + lane*16 ; row=p>>7 ; pre-swizzle source.
  const u16* pa[4];
  const u16* pb4[4];
  unsigned ldsA[4], ldsB[4];
#pragma unroll
  for (int j = 0; j < 4; ++j) {
    int p = (wid * 4 + j) * 1024 + lane * 16;
    int row = p >> 7;
    int ninner = (p & 127) ^ ((row & 7) << 4);
    pa[j] = zh + (size_t)(row0 + row) * DIM + (ninner >> 1);
    pb4[j] = ch + (size_t)(col0 + row) * DIM + (ninner >> 1);
    ldsA[j] = (wid * 4 + j) * 512;  // halves
    ldsB[j] = (wid * 4 + j) * 512;
  }

  // ds_read byte offsets (swizzled), constant across K-tiles
  int pbA[4][2], pbB[4][2];
#pragma unroll
  for (int m = 0; m < 4; ++m) {
#pragma unroll
    for (int k2 = 0; k2 < 2; ++k2) {
      int khalf = k2 * 32 + (lane >> 4) * 8;
      int R = wr + m * 16 + (lane & 15);
      pbA[m][k2] = (R * 128 + khalf * 2) ^ ((R & 7) << 4);
      int C = wc + m * 16 + (lane & 15);
      pbB[m][k2] = (C * 128 + khalf * 2) ^ ((C & 7) << 4);
    }
  }

  for (int t = 0; t < DIM / BKH; ++t) {
    __syncthreads();  // previous tile's reads done
#pragma unroll
    for (int j = 0; j < 4; ++j) {
      GLOAD_LDS16(pa[j], Ah + ldsA[j]);
      GLOAD_LDS16(pb4[j], Bh + ldsB[j]);
      pa[j] += BKH;
      pb4[j] += BKH;
    }
    __syncthreads();  // compiler drains vmcnt before barrier
#pragma unroll
    for (int k2 = 0; k2 < 2; ++k2) {
      half8 af[4], bf[4];
#pragma unroll
      for (int m = 0; m < 4; ++m)
        af[m] = *(const half8*)((const char*)Ah + pbA[m][k2]);
#pragma unroll
      for (int n = 0; n < 4; ++n)
        bf[n] = *(const half8*)((const char*)Bh + pbB[n][k2]);
#pragma unroll
      for (int m = 0; m < 4; ++m)
#pragma unroll
        for (int n = 0; n < 4; ++n)
          acc[m][n] = __builtin_amdgcn_mfma_f32_16x16x32_f16(af[m], bf[n],
                                                             acc[m][n], 0, 0, 0);
    }
  }

  // epilogue pass 1: per-row max over this wave's 64 cols -> LDS
#pragma unroll
  for (int m = 0; m < 4; ++m) {
#pragma unroll
    for (int rg = 0; rg < 4; ++rg) {
      float mx = acc[m][0][rg];
#pragma unroll
      for (int n = 1; n < 4; ++n) mx = fmaxf(mx, acc[m][n][rg]);
#pragma unroll
      for (int s = 1; s <= 8; s <<= 1) mx = fmaxf(mx, __shfl_xor(mx, s, 64));
      int Rloc = wr + m * 16 + (lane >> 4) * 4 + rg;
      if ((lane & 15) == 0) rmaxw[wid & 1][Rloc] = mx;
    }
  }
  __syncthreads();
  // epilogue pass 2: combined 128-col tile max -> tilemax + threshold append
#pragma unroll
  for (int m = 0; m < 4; ++m) {
#pragma unroll
    for (int rg = 0; rg < 4; ++rg) {
      int Rloc = wr + m * 16 + (lane >> 4) * 4 + rg;
      int grow = row0 + Rloc;
      float gm = fmaxf(rmaxw[0][Rloc], rmaxw[1][Rloc]);
      if ((wid & 1) == 0 && (lane & 15) == 0)
        tilemax[(size_t)blockIdx.x * N_ROWS + grow] = gm;
      float thr = gm - DELTA_A;
#pragma unroll
      for (int n = 0; n < 4; ++n) {
        float v = acc[m][n][rg];
        if (v >= thr) {
          int code = col0 + wc + n * 16 + (lane & 15);
          uint2 e = make_uint2(((unsigned)grow << 13) | (unsigned)code,
                               __float_as_uint(v));
          int p = atomicAdd(&ocnt, 1);
          if (p < OVCAP) obuf[p] = e;
          else {
            int g = atomicAdd(ovcnt, 1);
            if (g < gcap) ovlist[g] = e;
          }
        }
      }
    }
  }
  __syncthreads();
  int n = ocnt < OVCAP ? ocnt : OVCAP;
  if (tid == 0) gbase = atomicAdd(ovcnt, n);
  __syncthreads();
  for (int i = tid; i < n; i += 256) {
    int g = gbase + i;
    if (g < gcap) ovlist[g] = obuf[i];
  }
}

// ---------------- merge: per-row global max -> filter threshold; init win -----------
__global__ __launch_bounds__(256)
void vq_merge(const float* __restrict__ tilemax, float* __restrict__ mthr,
              unsigned long long* __restrict__ win) {
  int row = blockIdx.x * 256 + threadIdx.x;
  float g = -1e30f;
  for (int t = 0; t < 64; ++t) g = fmaxf(g, tilemax[(size_t)t * N_ROWS + row]);
  mthr[row] = g - DELTA_A;
  win[row] = ~0ULL;
}

__global__ __launch_bounds__(256)
void vq_init(unsigned long long* __restrict__ win) {
  int row = blockIdx.x * 256 + threadIdx.x;
  win[row] = ~0ULL;
}

// ---------------- overflow: filter + exact fp32 chain re-rank ----------------
__global__ __launch_bounds__(256)
void vq_overflow(const float* __restrict__ z, const float* __restrict__ cb,
                 const float* __restrict__ s1, const float* __restrict__ mthr,
                 const uint2* __restrict__ ovlist, const int* __restrict__ ovcnt,
                 int gcap, unsigned long long* __restrict__ win) {
  int n = *ovcnt;
  if (n > gcap) n = gcap;
  for (int i = blockIdx.x * 256 + threadIdx.x; i < n; i += gridDim.x * 256) {
    uint2 e = ovlist[i];
    int row = e.x >> 13;
    int code = e.x & 8191;
    if (__uint_as_float(e.y) < mthr[row]) continue;
    const float* zp = z + (size_t)row * DIM;
    const float* cp = cb + (size_t)code * DIM;
    float acc = 0.f;
    for (int k = 0; k < DIM; k += 4) {
      float4 zv = *(const float4*)(zp + k);
      float4 cv = *(const float4*)(cp + k);
      acc = fmaf(zv.x, cv.x, acc);
      acc = fmaf(zv.y, cv.y, acc);
      acc = fmaf(zv.z, cv.z, acc);
      acc = fmaf(zv.w, cv.w, acc);
    }
    float dq = __fsub_rn(s1[row], __fmul_rn(2.0f, acc));
    unsigned long long key =
        ((unsigned long long)__float_as_uint(dq) << 32) | (unsigned)code;
    atomicMin(&win[row], key);
  }
}

// ---------------- fallback: gated full exact scan (overflow safety) ----------------
__global__ __launch_bounds__(256)
void vq_fallback(const float* __restrict__ z, const float* __restrict__ cb,
                 const float* __restrict__ s1, const int* __restrict__ ovcnt,
                 int gcap, int force, unsigned long long* __restrict__ win) {
  if (!force && *ovcnt <= gcap) return;
  __shared__ float zrow[DIM];
  __shared__ unsigned long long red[256];
  for (int row = blockIdx.x; row < N_ROWS; row += gridDim.x) {
    __syncthreads();
    for (int t = threadIdx.x; t < DIM; t += 256) zrow[t] = z[(size_t)row * DIM + t];
    __syncthreads();
    float s1v = s1[row];
    unsigned long long best = ~0ULL;
    for (int j = threadIdx.x; j < K_CODES; j += 256) {
      const float* cp = cb + (size_t)j * DIM;
      float acc = 0.f;
      for (int k = 0; k < DIM; ++k) acc = fmaf(zrow[k], cp[k], acc);
      float dq = __fsub_rn(s1v, __fmul_rn(2.0f, acc));
      unsigned long long key =
          ((unsigned long long)__float_as_uint(dq) << 32) | (unsigned)j;
      if (key < best) best = key;
    }
    red[threadIdx.x] = best;
    __syncthreads();
    for (int s = 128; s > 0; s >>= 1) {
      if (threadIdx.x < s && red[threadIdx.x + s] < red[threadIdx.x])
        red[threadIdx.x] = red[threadIdx.x + s];
      __syncthreads();
    }
    if (threadIdx.x == 0) atomicMin(&win[row], red[0]);
    __syncthreads();
  }
}

// ---------------- out: gather z_q, write indices, per-row loss (f64) ----------------
__global__ __launch_bounds__(256)
void vq_out(const float* __restrict__ z, const float* __restrict__ cb,
            const unsigned long long* __restrict__ win, float* __restrict__ out,
            double* __restrict__ loss64) {
  int wid = threadIdx.x >> 6, lane = threadIdx.x & 63;
  int row = blockIdx.x * 4 + wid;
  int I1 = (int)(win[row] & 8191ULL);
  const float* zp = z + (size_t)row * DIM + lane * 8;
  const float* cp = cb + (size_t)I1 * DIM + lane * 8;
  float4 z0 = *(const float4*)zp, z1 = *(const float4*)(zp + 4);
  float4 c0 = *(const float4*)cp, c1 = *(const float4*)(cp + 4);
  *(float4*)&out[(size_t)row * DIM + lane * 8] = c0;
  *(float4*)&out[(size_t)row * DIM + lane * 8 + 4] = c1;
  double s = 0.0, d;
  d = (double)z0.x - c0.x; s += d * d;
  d = (double)z0.y - c0.y; s += d * d;
  d = (double)z0.z - c0.z; s += d * d;
  d = (double)z0.w - c0.w; s += d * d;
  d = (double)z1.x - c1.x; s += d * d;
  d = (double)z1.y - c1.y; s += d * d;
  d = (double)z1.z - c1.z; s += d * d;
  d = (double)z1.w - c1.w; s += d * d;
#pragma unroll
  for (int m = 32; m >= 1; m >>= 1) s += __shfl_down(s, m, 64);
  if (lane == 0) {
    loss64[row] = s;
    out[(size_t)N_ROWS * DIM + row] = (float)I1;
  }
}

// ---------------- loss: deterministic reduction ----------------
__global__ __launch_bounds__(1024)
void vq_loss(const double* __restrict__ loss64, float* __restrict__ out) {
  __shared__ double sd[1024];
  double s = 0.0;
  for (int i = threadIdx.x; i < N_ROWS; i += 1024) s += loss64[i];
  sd[threadIdx.x] = s;
  __syncthreads();
  for (int k = 512; k > 0; k >>= 1) {
    if (threadIdx.x < k) sd[threadIdx.x] += sd[threadIdx.x + k];
    __syncthreads();
  }
  if (threadIdx.x == 0)
    out[(size_t)N_ROWS * DIM + N_ROWS] =
        (float)(BETA * sd[0] / ((double)N_ROWS * (double)DIM));
}

extern "C" void kernel_launch(void* const* d_in, const int* in_sizes, int n_in,
                              void* d_out, int out_size, void* d_ws, size_t ws_size,
                              hipStream_t stream) {
  const float* z = (const float*)d_in[0];
  const float* cb = (const float*)d_in[1];
  float* out = (float*)d_out;
  char* ws = (char*)d_ws;

  // fast-path ws layout
  const size_t OFF_ZH = 0;                         // 33,554,432
  const size_t OFF_CH = 33554432;                  //  8,388,608
  const size_t OFF_S1 = 41943040;                  //    131,072
  const size_t OFF_MT = 42074112;                  //    131,072
  const size_t OFF_WIN = 42205184;                 //    262,144
  const size_t OFF_L64 = 42467328;                 //    262,144
  const size_t OFF_TM = 42729472;                  //  8,388,608
  const size_t OFF_OC = 51118080;                  //         16
  const size_t OFF_OV = 51118096;                  // list...
  const size_t MIN_FAST = OFF_OV + (size_t)8 * 1024 * 1024;

  if (ws_size >= MIN_FAST) {
    u16* zh = (u16*)(ws + OFF_ZH);
    u16* ch = (u16*)(ws + OFF_CH);
    float* s1f = (float*)(ws + OFF_S1);
    float* mthr = (float*)(ws + OFF_MT);
    unsigned long long* win = (unsigned long long*)(ws + OFF_WIN);
    double* loss64 = (double*)(ws + OFF_L64);
    float* tilemax = (float*)(ws + OFF_TM);
    int* ovcnt = (int*)(ws + OFF_OC);
    uint2* ovlist = (uint2*)(ws + OFF_OV);
    long long gc = (long long)(ws_size - OFF_OV) / 8;
    if (gc > 6 * 1024 * 1024) gc = 6 * 1024 * 1024;
    int gcap = (int)gc;

    vq_cvt<<<N_ROWS * DIM / 8 / 256, 256, 0, stream>>>(z, zh, 1.0f,
                                                       N_ROWS * DIM / 8, ovcnt);
    vq_cvt<<<K_CODES * DIM / 8 / 256, 256, 0, stream>>>(cb, ch, 4096.0f,
                                                        K_CODES * DIM / 8, nullptr);
    vq_s1<<<N_ROWS / 256, 256, 0, stream>>>(z, s1f);
    vq_gemm<<<dim3(K_CODES / 128, N_ROWS / 128), 256, 0, stream>>>(
        zh, ch, tilemax, ovlist, ovcnt, gcap);
    vq_merge<<<N_ROWS / 256, 256, 0, stream>>>(tilemax, mthr, win);
    vq_overflow<<<2048, 256, 0, stream>>>(z, cb, s1f, mthr, ovlist, ovcnt, gcap, win);
    vq_fallback<<<2048, 256, 0, stream>>>(z, cb, s1f, ovcnt, gcap, 0, win);
    vq_out<<<N_ROWS / 4, 256, 0, stream>>>(z, cb, win, out, loss64);
    vq_loss<<<1, 1024, 0, stream>>>(loss64, out);
  } else {
    // tiny-ws safe path: exact full scan
    float* s1f = (float*)(ws + 0);                                 // 131,072
    unsigned long long* win = (unsigned long long*)(ws + 131072);  // 262,144
    double* loss64 = (double*)(ws + 393216);                       // 262,144
    vq_s1<<<N_ROWS / 256, 256, 0, stream>>>(z, s1f);
    vq_init<<<N_ROWS / 256, 256, 0, stream>>>(win);
    vq_fallback<<<2048, 256, 0, stream>>>(z, cb, s1f, nullptr, 0, 1, win);
    vq_out<<<N_ROWS / 4, 256, 0, stream>>>(z, cb, win, out, loss64);
    vq_loss<<<1, 1024, 0, stream>>>(loss64, out);
  }
}